// Round 3
// baseline (605.500 us; speedup 1.0000x reference)
//
#include <hip/hip_runtime.h>

#define NN 100000
#define NE 1600000
#define F  128
#define NB 391           // ceil(NN/256) blocks for node scan
#define NBK 782          // buckets = ceil(NN/128), bucket = dst>>7
#define BCAP 2560        // per-bucket edge capacity (mean 2046, +11 sigma)

constexpr float EPS   = 1e-5f;
constexpr float SLOPE = 0.01f;

typedef __attribute__((ext_vector_type(8))) short short8;
typedef __attribute__((ext_vector_type(4))) float f32x4;

__device__ inline unsigned int bf16rne(float f) {
    unsigned int u = __float_as_uint(f);
    return (u + 0x7fffu + ((u >> 16) & 1u)) >> 16;
}

// ---------------- init: zero bucket counters + stats ----------------
__global__ void k_init(unsigned int* __restrict__ bcnt, float* __restrict__ stats) {
    int i = blockIdx.x * blockDim.x + threadIdx.x;
    if (i < NBK) bcnt[i] = 0u;
    if (i < 2 * F) stats[i] = 0.0f;
}

// ---------------- W prep: fragment-ordered bf16 tiles ----------------
// Wt[idx], idx = ((kk*8+n)*64 + lane)*4 + p : packs W[k][c],W[k+1][c]
// with k = kk*32 + (lane>>4)*8 + 2p, c = n*16 + (lane&15)
__global__ void k_wprep(const float* __restrict__ Wm, unsigned int* __restrict__ Wt) {
    int idx = blockIdx.x * 256 + threadIdx.x;   // 8192 total
    int p = idx & 3, lane = (idx >> 2) & 63, n = (idx >> 8) & 7, kk = idx >> 11;
    int k0 = kk * 32 + (lane >> 4) * 8 + 2 * p;
    int c  = n * 16 + (lane & 15);
    unsigned int lo = bf16rne(Wm[k0 * F + c]);
    unsigned int hi = bf16rne(Wm[(k0 + 1) * F + c]);
    Wt[idx] = lo | (hi << 16);
}

// ---------------- bucket edges by dst>>7 (append, dense writes) ----------------
__global__ void k_bucket(const int* __restrict__ ei, unsigned int* __restrict__ bcnt,
                         unsigned int* __restrict__ bbuf) {
    int e = blockIdx.x * 256 + threadIdx.x;
    if (e < NE) {
        int s = ei[e], d = ei[NE + e];
        int bkt = d >> 7;
        unsigned int pos = atomicAdd(&bcnt[bkt], 1u);
        if (pos < BCAP) bbuf[(size_t)bkt * BCAP + pos] = ((unsigned int)(d & 127) << 24) | (unsigned int)s;
    }
}

// ---------------- per-bucket histogram -> degrees (dense writes) ----------------
__global__ __launch_bounds__(256) void k_bhist(const unsigned int* __restrict__ bcnt,
                                               const unsigned int* __restrict__ bbuf,
                                               unsigned int* __restrict__ deg_i) {
    __shared__ unsigned int h[128];
    const int bkt = blockIdx.x;
    if (threadIdx.x < 128) h[threadIdx.x] = 0u;
    __syncthreads();
    unsigned int n = bcnt[bkt];
    if (n > BCAP) n = BCAP;
    const unsigned int* bp = bbuf + (size_t)bkt * BCAP;
    for (unsigned int i = threadIdx.x; i < n; i += 256) atomicAdd(&h[bp[i] >> 24], 1u);
    __syncthreads();
    if (threadIdx.x < 128) {
        int node = bkt * 128 + threadIdx.x;
        if (node < NN) deg_i[node] = h[threadIdx.x];
    }
}

// ---------------- dis = rsqrt(deg+1) ----------------
__global__ void k_dis(const unsigned int* __restrict__ deg_i, float* __restrict__ dis) {
    int i = blockIdx.x * blockDim.x + threadIdx.x;
    if (i < NN) dis[i] = rsqrtf((float)(deg_i[i] + 1u));
}

// ---------------- prefix scan (3 kernels) -> row_start ----------------
__global__ void k_scanA(const unsigned int* __restrict__ deg_i, unsigned int* __restrict__ scan,
                        unsigned int* __restrict__ bsums) {
    __shared__ unsigned int s[256];
    const int t = threadIdx.x;
    const int i = blockIdx.x * 256 + t;
    unsigned int v = (i < NN) ? deg_i[i] : 0u;
    s[t] = v;
    __syncthreads();
    for (int off = 1; off < 256; off <<= 1) {
        unsigned int a = (t >= off) ? s[t - off] : 0u;
        __syncthreads();
        s[t] += a;
        __syncthreads();
    }
    if (i < NN) scan[i] = s[t];
    if (t == 255) bsums[blockIdx.x] = s[255];
}

__global__ void k_scanB(const unsigned int* __restrict__ bsums, unsigned int* __restrict__ boff) {
    __shared__ unsigned int s[512];
    const int t = threadIdx.x;
    unsigned int v = (t < NB) ? bsums[t] : 0u;
    s[t] = v;
    __syncthreads();
    for (int off = 1; off < 512; off <<= 1) {
        unsigned int a = (t >= off) ? s[t - off] : 0u;
        __syncthreads();
        s[t] += a;
        __syncthreads();
    }
    if (t < NB) boff[t] = s[t] - v;
}

__global__ void k_scanC(const unsigned int* __restrict__ scan, const unsigned int* __restrict__ boff,
                        int* __restrict__ row_start) {
    int i = blockIdx.x * 256 + threadIdx.x;
    if (i < NN) row_start[i + 1] = (int)(scan[i] + boff[i >> 8]);
    if (i == 0) row_start[0] = 0;
}

// ---------------- per-bucket fill: csr writes land in contiguous span ----------------
__global__ __launch_bounds__(256) void k_bfill(const unsigned int* __restrict__ bcnt,
                                               const unsigned int* __restrict__ bbuf,
                                               const int* __restrict__ row_start,
                                               int* __restrict__ csr) {
    __shared__ unsigned int cur[128];
    const int bkt = blockIdx.x;
    if (threadIdx.x < 128) {
        int node = bkt * 128 + threadIdx.x;
        cur[threadIdx.x] = (node < NN) ? (unsigned int)row_start[node] : 0u;
    }
    __syncthreads();
    unsigned int n = bcnt[bkt];
    if (n > BCAP) n = BCAP;
    const unsigned int* bp = bbuf + (size_t)bkt * BCAP;
    for (unsigned int i = threadIdx.x; i < n; i += 256) {
        unsigned int v = bp[i];
        unsigned int pos = atomicAdd(&cur[v >> 24], 1u);
        csr[pos] = (int)(v & 0xFFFFFFu);
    }
}

// ---------------- MFMA GEMM: g = bf16(x @ W) * dis, row-major bf16 ----------------
__global__ __launch_bounds__(256) void k_gemm(const float* __restrict__ x,
                                              const unsigned int* __restrict__ Wt,
                                              const float* __restrict__ dis,
                                              unsigned short* __restrict__ g16) {
    __shared__ uint4 wlds[2048];   // 32 KB, fragment-ordered bf16 W^T
    const int tid = threadIdx.x;
    const int lane = tid & 63, wave = tid >> 6;

    // stage W tiles (L2-hot, once per block)
    const uint4* Wt4 = (const uint4*)Wt;
#pragma unroll
    for (int i = 0; i < 8; ++i) wlds[tid + i * 256] = Wt4[tid + i * 256];

    // A fragments straight from global x (coalesced at line granularity)
    const int rbase = blockIdx.x * 128 + wave * 32;
    short8 afr[2][4];
#pragma unroll
    for (int m = 0; m < 2; ++m) {
        int row = rbase + m * 16 + (lane & 15);
        if (row >= NN) row = NN - 1;            // clamp; stores guarded
        const float* xp = x + (size_t)row * F;
#pragma unroll
        for (int kk = 0; kk < 4; ++kk) {
            int kb = kk * 32 + (lane >> 4) * 8;
            float4 v0 = *(const float4*)(xp + kb);
            float4 v1 = *(const float4*)(xp + kb + 4);
            short8 a;
            a[0] = (short)bf16rne(v0.x); a[1] = (short)bf16rne(v0.y);
            a[2] = (short)bf16rne(v0.z); a[3] = (short)bf16rne(v0.w);
            a[4] = (short)bf16rne(v1.x); a[5] = (short)bf16rne(v1.y);
            a[6] = (short)bf16rne(v1.z); a[7] = (short)bf16rne(v1.w);
            afr[m][kk] = a;
        }
    }
    __syncthreads();

    f32x4 acc[2][8];
#pragma unroll
    for (int m = 0; m < 2; ++m)
#pragma unroll
        for (int n = 0; n < 8; ++n) { f32x4 z = {0.f, 0.f, 0.f, 0.f}; acc[m][n] = z; }

#pragma unroll
    for (int kk = 0; kk < 4; ++kk) {
        union { uint4 u; short8 s; } bfr[8];
#pragma unroll
        for (int n = 0; n < 8; ++n) bfr[n].u = wlds[(kk * 8 + n) * 64 + lane];
#pragma unroll
        for (int m = 0; m < 2; ++m)
#pragma unroll
            for (int n = 0; n < 8; ++n)
                acc[m][n] = __builtin_amdgcn_mfma_f32_16x16x32_bf16(afr[m][kk], bfr[n].s, acc[m][n], 0, 0, 0);
    }

    // epilogue: scale by dis[row], store bf16
    float dv[2][4];
#pragma unroll
    for (int m = 0; m < 2; ++m)
#pragma unroll
        for (int r = 0; r < 4; ++r) {
            int row = rbase + m * 16 + (lane >> 4) * 4 + r;
            dv[m][r] = (row < NN) ? dis[row] : 0.0f;
        }
#pragma unroll
    for (int m = 0; m < 2; ++m)
#pragma unroll
        for (int n = 0; n < 8; ++n)
#pragma unroll
            for (int r = 0; r < 4; ++r) {
                int row = rbase + m * 16 + (lane >> 4) * 4 + r;
                if (row < NN) {
                    int col = n * 16 + (lane & 15);
                    g16[(size_t)row * F + col] = (unsigned short)bf16rne(acc[m][n][r] * dv[m][r]);
                }
            }
}

// ---------------- gather: out = b + dis[n]*(g[n] + sum g[src]) ----------------
__global__ __launch_bounds__(256) void k_gather(const unsigned int* __restrict__ g,
                                                const int* __restrict__ csr,
                                                const int* __restrict__ row_start,
                                                const float* __restrict__ dis,
                                                const float* __restrict__ b,
                                                float* __restrict__ out) {
    const int lane = threadIdx.x & 63;
    const int node = blockIdx.x * 4 + (threadIdx.x >> 6);
    if (node >= NN) return;

    unsigned int u = g[(long)node * 64 + lane];
    float acc0 = __uint_as_float(u << 16);
    float acc1 = __uint_as_float(u & 0xffff0000u);

    int j = row_start[node];
    const int e = row_start[node + 1];
    for (; j + 1 < e; j += 2) {
        int s0 = csr[j], s1 = csr[j + 1];
        unsigned int v0 = g[(long)s0 * 64 + lane];
        unsigned int v1 = g[(long)s1 * 64 + lane];
        acc0 += __uint_as_float(v0 << 16);
        acc1 += __uint_as_float(v0 & 0xffff0000u);
        acc0 += __uint_as_float(v1 << 16);
        acc1 += __uint_as_float(v1 & 0xffff0000u);
    }
    if (j < e) {
        int s = csr[j];
        unsigned int v = g[(long)s * 64 + lane];
        acc0 += __uint_as_float(v << 16);
        acc1 += __uint_as_float(v & 0xffff0000u);
    }
    float d = dis[node];
    float2 r;
    r.x = b[lane * 2]     + d * acc0;
    r.y = b[lane * 2 + 1] + d * acc1;
    *(float2*)&out[(long)node * F + lane * 2] = r;
}

// ---------------- per-feature sums / sumsq ----------------
__global__ __launch_bounds__(256) void k_stats(const float* __restrict__ agg,
                                               float* __restrict__ sums,
                                               float* __restrict__ sumsq) {
    __shared__ float red[2][F];
    const int tx = threadIdx.x & 127;
    const int ty = threadIdx.x >> 7;
    float s = 0.0f, s2 = 0.0f;
    for (int row = blockIdx.x * 2 + ty; row < NN; row += gridDim.x * 2) {
        float v = agg[(long)row * F + tx];
        s += v;
        s2 += v * v;
    }
    red[ty][tx] = s;
    __syncthreads();
    if (ty == 0) atomicAdd(&sums[tx], s + red[1][tx]);
    __syncthreads();
    red[ty][tx] = s2;
    __syncthreads();
    if (ty == 0) atomicAdd(&sumsq[tx], s2 + red[1][tx]);
}

// ---------------- finalize stats -> per-feature affine ----------------
__global__ void k_finstats(const float* __restrict__ sums, const float* __restrict__ sumsq,
                           const float* __restrict__ gw, const float* __restrict__ gb,
                           const float* __restrict__ gms,
                           float* __restrict__ A, float* __restrict__ Bc) {
    int f = threadIdx.x;
    if (f < F) {
        const float invn = 1.0f / (float)NN;
        float mean = sums[f] * invn;
        float ms = mean * gms[f];
        float var = sumsq[f] * invn - 2.0f * ms * mean + ms * ms;
        float inv = rsqrtf(var + EPS);
        float a = inv * gw[f];
        A[f] = a;
        Bc[f] = gb[f] - ms * a;
    }
}

// ---------------- in-place GraphNorm affine + LeakyReLU (float4) ----------------
__global__ void k_final(float* __restrict__ out, const float* __restrict__ A,
                        const float* __restrict__ Bc) {
    const long total = (long)NN * F / 4;
    float4* o4 = (float4*)out;
    const float4* A4 = (const float4*)A;
    const float4* B4 = (const float4*)Bc;
    for (long i = (long)blockIdx.x * blockDim.x + threadIdx.x; i < total;
         i += (long)gridDim.x * blockDim.x) {
        int f4 = (int)(i & 31);
        float4 v = o4[i];
        float4 a = A4[f4];
        float4 bc = B4[f4];
        v.x = v.x * a.x + bc.x; v.x = v.x > 0.f ? v.x : SLOPE * v.x;
        v.y = v.y * a.y + bc.y; v.y = v.y > 0.f ? v.y : SLOPE * v.y;
        v.z = v.z * a.z + bc.z; v.z = v.z > 0.f ? v.z : SLOPE * v.z;
        v.w = v.w * a.w + bc.w; v.w = v.w > 0.f ? v.w : SLOPE * v.w;
        o4[i] = v;
    }
}

// ---------------- edge_index passthrough as float (int4 -> float4) ----------------
__global__ void k_eicopy(const int* __restrict__ ei, float* __restrict__ out1) {
    const long total = 2L * NE / 4;
    const int4* i4 = (const int4*)ei;
    float4* o4 = (float4*)out1;
    for (long i = (long)blockIdx.x * blockDim.x + threadIdx.x; i < total;
         i += (long)gridDim.x * blockDim.x) {
        int4 v = i4[i];
        float4 r;
        r.x = (float)v.x; r.y = (float)v.y; r.z = (float)v.z; r.w = (float)v.w;
        o4[i] = r;
    }
}

extern "C" void kernel_launch(void* const* d_in, const int* in_sizes, int n_in,
                              void* d_out, int out_size, void* d_ws, size_t ws_size,
                              hipStream_t stream) {
    const float* x   = (const float*)d_in[0];
    const int*   ei  = (const int*)d_in[1];
    const float* Wm  = (const float*)d_in[2];
    const float* b   = (const float*)d_in[3];
    const float* gw  = (const float*)d_in[4];
    const float* gb  = (const float*)d_in[5];
    const float* gms = (const float*)d_in[6];

    float* out  = (float*)d_out;                 // region0: NN*F, region1: 2*NE
    float* out1 = out + (size_t)NN * F;

    // ws layout (u32 units). bbuf aliases g: bbuf consumed by k_bfill before k_gemm writes g.
    unsigned int* wsu   = (unsigned int*)d_ws;
    unsigned int* g     = wsu;                          // NN*64 u32 (25.6 MB)
    unsigned int* bbuf  = wsu;                          // NBK*BCAP = 2.0M u32 (8 MB) — alias
    unsigned int* deg_i = g + (size_t)NN * 64;          // NN
    unsigned int* scan  = deg_i + NN;                   // NN
    unsigned int* bsums = scan + NN;                    // 512
    unsigned int* boff  = bsums + 512;                  // 512
    unsigned int* bcnt  = boff + 512;                   // 1024 (NBK)
    int* row_start      = (int*)(bcnt + 1024);          // NN+2
    int* csr            = row_start + NN + 2;           // NE
    float* dis          = (float*)(csr + NE);           // NN
    float* stats        = dis + NN;                     // 512
    unsigned int* Wt    = (unsigned int*)(stats + 512); // 8192
    float* sums  = stats;
    float* sumsq = stats + F;
    float* A     = stats + 2 * F;
    float* Bc    = stats + 3 * F;

    k_init<<<4, 256, 0, stream>>>(bcnt, stats);
    k_wprep<<<32, 256, 0, stream>>>(Wm, Wt);
    k_bucket<<<(NE + 255) / 256, 256, 0, stream>>>(ei, bcnt, bbuf);
    k_bhist<<<NBK, 256, 0, stream>>>(bcnt, bbuf, deg_i);
    k_dis<<<(NN + 255) / 256, 256, 0, stream>>>(deg_i, dis);
    k_scanA<<<NB, 256, 0, stream>>>(deg_i, scan, bsums);
    k_scanB<<<1, 512, 0, stream>>>(bsums, boff);
    k_scanC<<<NB, 256, 0, stream>>>(scan, boff, row_start);
    k_bfill<<<NBK, 256, 0, stream>>>(bcnt, bbuf, row_start, csr);
    k_gemm<<<(NN + 127) / 128, 256, 0, stream>>>(x, Wt, dis, (unsigned short*)g);
    k_gather<<<(NN + 3) / 4, 256, 0, stream>>>(g, csr, row_start, dis, b, out);
    k_stats<<<1024, 256, 0, stream>>>(out, sums, sumsq);
    k_finstats<<<1, F, 0, stream>>>(sums, sumsq, gw, gb, gms, A, Bc);
    k_final<<<2048, 256, 0, stream>>>(out, A, Bc);
    k_eicopy<<<2048, 256, 0, stream>>>(ei, out1);
}

// Round 4
// 272.672 us; speedup vs baseline: 2.2206x; 2.2206x over previous
//
#include <hip/hip_runtime.h>

#define NN 100000
#define NE 1600000
#define F  128

// radix partition params
#define SH   10                 // bucket = dst >> 10
#define NPB  1024               // nodes per bucket
#define NBKT 98                 // ceil(NN/1024)
#define B1   256                // pass-1 blocks
#define CH1  6250               // NE / B1 exactly

constexpr float EPS   = 1e-5f;
constexpr float SLOPE = 0.01f;

typedef __attribute__((ext_vector_type(8))) short short8;
typedef __attribute__((ext_vector_type(4))) float f32x4;

__device__ inline unsigned int bf16rne(float f) {
    unsigned int u = __float_as_uint(f);
    return (u + 0x7fffu + ((u >> 16) & 1u)) >> 16;
}
__device__ inline float blo(unsigned int u) { return __uint_as_float(u << 16); }
__device__ inline float bhi(unsigned int u) { return __uint_as_float(u & 0xffff0000u); }

// ---------------- init: zero stats ----------------
__global__ void k_init(float* __restrict__ stats) {
    int i = threadIdx.x;
    if (i < 2 * F) stats[i] = 0.0f;
}

// ---------------- W prep: fragment-ordered bf16 tiles ----------------
__global__ void k_wprep(const float* __restrict__ Wm, unsigned int* __restrict__ Wt) {
    int idx = blockIdx.x * 256 + threadIdx.x;   // 8192 total
    int p = idx & 3, lane = (idx >> 2) & 63, n = (idx >> 8) & 7, kk = idx >> 11;
    int k0 = kk * 32 + (lane >> 4) * 8 + 2 * p;
    int c  = n * 16 + (lane & 15);
    unsigned int lo = bf16rne(Wm[k0 * F + c]);
    unsigned int hi = bf16rne(Wm[(k0 + 1) * F + c]);
    Wt[idx] = lo | (hi << 16);
}

// ---------------- pass 1a: per-block bucket histogram (LDS, no global atomics) ----------------
__global__ __launch_bounds__(1024) void k_hist1(const int* __restrict__ dst,
                                                unsigned int* __restrict__ mat) {
    __shared__ unsigned int h[NBKT];
    if (threadIdx.x < NBKT) h[threadIdx.x] = 0u;
    __syncthreads();
    const int e0 = blockIdx.x * CH1;
    for (int i = threadIdx.x; i < CH1; i += 1024)
        atomicAdd(&h[dst[e0 + i] >> SH], 1u);
    __syncthreads();
    if (threadIdx.x < NBKT) mat[threadIdx.x * B1 + blockIdx.x] = h[threadIdx.x];
}

// ---------------- pass 1b: exclusive scan of (bucket,block) matrix ----------------
__global__ __launch_bounds__(1024) void k_scan1(unsigned int* __restrict__ mat) {
    __shared__ unsigned int ps[1024];
    const int t = threadIdx.x;
    const int total = NBKT * B1;          // 25088
    const int SER = 25;
    int lo = t * SER, hi = min(lo + SER, total);
    unsigned int loc[SER];
    unsigned int s = 0u;
    for (int i = lo; i < hi; ++i) { loc[i - lo] = mat[i]; s += loc[i - lo]; }
    ps[t] = s;
    __syncthreads();
    for (int off = 1; off < 1024; off <<= 1) {
        unsigned int a = (t >= off) ? ps[t - off] : 0u;
        __syncthreads();
        ps[t] += a;
        __syncthreads();
    }
    unsigned int run = (t == 0) ? 0u : ps[t - 1];
    for (int i = lo; i < hi; ++i) { unsigned int v = loc[i - lo]; mat[i] = run; run += v; }
}

// ---------------- pass 1c: scatter edges into bucket segments ----------------
__global__ __launch_bounds__(1024) void k_scat1(const int* __restrict__ ei,
                                                const unsigned int* __restrict__ mat,
                                                unsigned int* __restrict__ ebuf) {
    __shared__ unsigned int cur[NBKT];
    if (threadIdx.x < NBKT) cur[threadIdx.x] = mat[threadIdx.x * B1 + blockIdx.x];
    __syncthreads();
    const int e0 = blockIdx.x * CH1;
    for (int i = threadIdx.x; i < CH1; i += 1024) {
        int s = ei[e0 + i];
        int d = ei[NE + e0 + i];
        unsigned int pos = atomicAdd(&cur[d >> SH], 1u);
        ebuf[pos] = ((unsigned int)(d & (NPB - 1)) << 17) | (unsigned int)s;
    }
}

// ---------------- pass 2: per-bucket degree/scan/row_start/dis + csr fill ----------------
__global__ __launch_bounds__(1024) void k_fill2(const unsigned int* __restrict__ mat,
                                                const unsigned int* __restrict__ ebuf,
                                                int* __restrict__ row_start,
                                                float* __restrict__ dis,
                                                int* __restrict__ csr) {
    __shared__ unsigned int hist[NPB];
    __shared__ unsigned int cur[NPB];
    __shared__ unsigned int ps[1024];
    const int t = threadIdx.x;
    const int bkt = blockIdx.x;
    const int nb0 = bkt << SH;
    hist[t] = 0u;
    __syncthreads();
    const unsigned int ebase = mat[bkt * B1];
    const unsigned int eend  = (bkt == NBKT - 1) ? (unsigned int)NE : mat[(bkt + 1) * B1];
    for (unsigned int i = ebase + t; i < eend; i += 1024)
        atomicAdd(&hist[ebuf[i] >> 17], 1u);
    __syncthreads();
    const unsigned int deg = hist[t];
    ps[t] = deg;
    __syncthreads();
    for (int off = 1; off < 1024; off <<= 1) {
        unsigned int a = (t >= off) ? ps[t - off] : 0u;
        __syncthreads();
        ps[t] += a;
        __syncthreads();
    }
    const unsigned int ex = (t == 0) ? 0u : ps[t - 1];
    cur[t] = ebase + ex;
    const int node = nb0 + t;
    if (node < NN) {
        row_start[node] = (int)(ebase + ex);
        dis[node] = rsqrtf((float)(deg + 1u));
    }
    if (bkt == NBKT - 1 && t == 0) row_start[NN] = NE;
    __syncthreads();
    for (unsigned int i = ebase + t; i < eend; i += 1024) {
        unsigned int v = ebuf[i];
        unsigned int pos = atomicAdd(&cur[v >> 17], 1u);
        csr[pos] = (int)(v & 0x1FFFFu);
    }
}

// ---------------- MFMA GEMM: g = bf16(x @ W) * dis, row-major bf16 ----------------
__global__ __launch_bounds__(256) void k_gemm(const float* __restrict__ x,
                                              const unsigned int* __restrict__ Wt,
                                              const float* __restrict__ dis,
                                              unsigned short* __restrict__ g16) {
    __shared__ uint4 wlds[2048];   // 32 KB, fragment-ordered bf16 W^T
    const int tid = threadIdx.x;
    const int lane = tid & 63, wave = tid >> 6;

    const uint4* Wt4 = (const uint4*)Wt;
#pragma unroll
    for (int i = 0; i < 8; ++i) wlds[tid + i * 256] = Wt4[tid + i * 256];

    const int rbase = blockIdx.x * 128 + wave * 32;
    short8 afr[2][4];
#pragma unroll
    for (int m = 0; m < 2; ++m) {
        int row = rbase + m * 16 + (lane & 15);
        if (row >= NN) row = NN - 1;            // clamp; stores guarded
        const float* xp = x + (size_t)row * F;
#pragma unroll
        for (int kk = 0; kk < 4; ++kk) {
            int kb = kk * 32 + (lane >> 4) * 8;
            float4 v0 = *(const float4*)(xp + kb);
            float4 v1 = *(const float4*)(xp + kb + 4);
            short8 a;
            a[0] = (short)bf16rne(v0.x); a[1] = (short)bf16rne(v0.y);
            a[2] = (short)bf16rne(v0.z); a[3] = (short)bf16rne(v0.w);
            a[4] = (short)bf16rne(v1.x); a[5] = (short)bf16rne(v1.y);
            a[6] = (short)bf16rne(v1.z); a[7] = (short)bf16rne(v1.w);
            afr[m][kk] = a;
        }
    }
    __syncthreads();

    f32x4 acc[2][8];
#pragma unroll
    for (int m = 0; m < 2; ++m)
#pragma unroll
        for (int n = 0; n < 8; ++n) { f32x4 z = {0.f, 0.f, 0.f, 0.f}; acc[m][n] = z; }

#pragma unroll
    for (int kk = 0; kk < 4; ++kk) {
        union { uint4 u; short8 s; } bfr[8];
#pragma unroll
        for (int n = 0; n < 8; ++n) bfr[n].u = wlds[(kk * 8 + n) * 64 + lane];
#pragma unroll
        for (int m = 0; m < 2; ++m)
#pragma unroll
            for (int n = 0; n < 8; ++n)
                acc[m][n] = __builtin_amdgcn_mfma_f32_16x16x32_bf16(afr[m][kk], bfr[n].s, acc[m][n], 0, 0, 0);
    }

    float dv[2][4];
#pragma unroll
    for (int m = 0; m < 2; ++m)
#pragma unroll
        for (int r = 0; r < 4; ++r) {
            int row = rbase + m * 16 + (lane >> 4) * 4 + r;
            dv[m][r] = (row < NN) ? dis[row] : 0.0f;
        }
#pragma unroll
    for (int m = 0; m < 2; ++m)
#pragma unroll
        for (int n = 0; n < 8; ++n)
#pragma unroll
            for (int r = 0; r < 4; ++r) {
                int row = rbase + m * 16 + (lane >> 4) * 4 + r;
                if (row < NN) {
                    int col = n * 16 + (lane & 15);
                    g16[(size_t)row * F + col] = (unsigned short)bf16rne(acc[m][n][r] * dv[m][r]);
                }
            }
}

// ---------------- gather: out = b + dis[n]*sum(g[src] over src ∪ {n}) ----------------
// wave per node; lanes 0-31 process source A, lanes 32-63 source B (uint2 each);
// self-loop appended to the source list; shfl_xor(32) combines the halves.
__global__ __launch_bounds__(256) void k_gather(const unsigned int* __restrict__ g,
                                                const int* __restrict__ csr,
                                                const int* __restrict__ row_start,
                                                const float* __restrict__ dis,
                                                const float* __restrict__ b,
                                                float* __restrict__ out) {
    const int lane = threadIdx.x & 63;
    const int node = blockIdx.x * 4 + (threadIdx.x >> 6);
    if (node >= NN) return;
    const int half = lane >> 5;
    const int cp = lane & 31;          // u32-pair index: features 4cp..4cp+3
    const int j = row_start[node];
    const int e = row_start[node + 1];
    const int L = e - j + 1;           // + self
    float a0 = 0.f, a1 = 0.f, a2 = 0.f, a3 = 0.f;
    for (int k = 0; k < L; k += 2) {
        int ia = j + k, ib = ia + 1;
        int ra = (ia < e) ? csr[ia] : node;
        int vb = (k + 1 < L);
        int rb = vb ? ((ib < e) ? csr[ib] : node) : 0;
        int row = half ? rb : ra;
        if (!half || vb) {
            uint2 v = *(const uint2*)&g[(size_t)row * 64 + 2 * cp];
            a0 += blo(v.x); a1 += bhi(v.x);
            a2 += blo(v.y); a3 += bhi(v.y);
        }
    }
    a0 += __shfl_xor(a0, 32); a1 += __shfl_xor(a1, 32);
    a2 += __shfl_xor(a2, 32); a3 += __shfl_xor(a3, 32);
    if (lane < 32) {
        float d = dis[node];
        float4 bb = *(const float4*)&b[4 * cp];
        float4 r;
        r.x = bb.x + d * a0; r.y = bb.y + d * a1;
        r.z = bb.z + d * a2; r.w = bb.w + d * a3;
        *(float4*)&out[(size_t)node * F + 4 * cp] = r;
    }
}

// ---------------- per-feature sums / sumsq ----------------
__global__ __launch_bounds__(256) void k_stats(const float* __restrict__ agg,
                                               float* __restrict__ sums,
                                               float* __restrict__ sumsq) {
    __shared__ float red[2][F];
    const int tx = threadIdx.x & 127;
    const int ty = threadIdx.x >> 7;
    float s = 0.0f, s2 = 0.0f;
    for (int row = blockIdx.x * 2 + ty; row < NN; row += gridDim.x * 2) {
        float v = agg[(long)row * F + tx];
        s += v;
        s2 += v * v;
    }
    red[ty][tx] = s;
    __syncthreads();
    if (ty == 0) atomicAdd(&sums[tx], s + red[1][tx]);
    __syncthreads();
    red[ty][tx] = s2;
    __syncthreads();
    if (ty == 0) atomicAdd(&sumsq[tx], s2 + red[1][tx]);
}

// ---------------- finalize stats -> per-feature affine ----------------
__global__ void k_finstats(const float* __restrict__ sums, const float* __restrict__ sumsq,
                           const float* __restrict__ gw, const float* __restrict__ gb,
                           const float* __restrict__ gms,
                           float* __restrict__ A, float* __restrict__ Bc) {
    int f = threadIdx.x;
    if (f < F) {
        const float invn = 1.0f / (float)NN;
        float mean = sums[f] * invn;
        float ms = mean * gms[f];
        float var = sumsq[f] * invn - 2.0f * ms * mean + ms * ms;
        float inv = rsqrtf(var + EPS);
        float a = inv * gw[f];
        A[f] = a;
        Bc[f] = gb[f] - ms * a;
    }
}

// ---------------- in-place GraphNorm affine + LeakyReLU (float4) ----------------
__global__ void k_final(float* __restrict__ out, const float* __restrict__ A,
                        const float* __restrict__ Bc) {
    const long total = (long)NN * F / 4;
    float4* o4 = (float4*)out;
    const float4* A4 = (const float4*)A;
    const float4* B4 = (const float4*)Bc;
    for (long i = (long)blockIdx.x * blockDim.x + threadIdx.x; i < total;
         i += (long)gridDim.x * blockDim.x) {
        int f4 = (int)(i & 31);
        float4 v = o4[i];
        float4 a = A4[f4];
        float4 bc = B4[f4];
        v.x = v.x * a.x + bc.x; v.x = v.x > 0.f ? v.x : SLOPE * v.x;
        v.y = v.y * a.y + bc.y; v.y = v.y > 0.f ? v.y : SLOPE * v.y;
        v.z = v.z * a.z + bc.z; v.z = v.z > 0.f ? v.z : SLOPE * v.z;
        v.w = v.w * a.w + bc.w; v.w = v.w > 0.f ? v.w : SLOPE * v.w;
        o4[i] = v;
    }
}

// ---------------- edge_index passthrough as float (int4 -> float4) ----------------
__global__ void k_eicopy(const int* __restrict__ ei, float* __restrict__ out1) {
    const long total = 2L * NE / 4;
    const int4* i4 = (const int4*)ei;
    float4* o4 = (float4*)out1;
    for (long i = (long)blockIdx.x * blockDim.x + threadIdx.x; i < total;
         i += (long)gridDim.x * blockDim.x) {
        int4 v = i4[i];
        float4 r;
        r.x = (float)v.x; r.y = (float)v.y; r.z = (float)v.z; r.w = (float)v.w;
        o4[i] = r;
    }
}

extern "C" void kernel_launch(void* const* d_in, const int* in_sizes, int n_in,
                              void* d_out, int out_size, void* d_ws, size_t ws_size,
                              hipStream_t stream) {
    const float* x   = (const float*)d_in[0];
    const int*   ei  = (const int*)d_in[1];
    const float* Wm  = (const float*)d_in[2];
    const float* b   = (const float*)d_in[3];
    const float* gw  = (const float*)d_in[4];
    const float* gb  = (const float*)d_in[5];
    const float* gms = (const float*)d_in[6];

    float* out  = (float*)d_out;                 // region0: NN*F, region1: 2*NE
    float* out1 = out + (size_t)NN * F;

    // ws layout (u32 units). ebuf aliases g: ebuf consumed by k_fill2 before k_gemm writes g.
    unsigned int* wsu   = (unsigned int*)d_ws;
    unsigned int* g     = wsu;                          // NN*64 u32 (25.6 MB)
    unsigned int* ebuf  = wsu;                          // NE u32 (6.4 MB) — alias of g
    unsigned int* mat   = g + (size_t)NN * 64;          // NBKT*B1 = 25088
    int* row_start      = (int*)(mat + NBKT * B1 + 64); // NN+1
    int* csr            = row_start + NN + 2;           // NE
    float* dis          = (float*)(csr + NE);           // NN
    float* stats        = dis + NN;                     // 512
    unsigned int* Wt    = (unsigned int*)(stats + 512); // 8192
    float* sums  = stats;
    float* sumsq = stats + F;
    float* A     = stats + 2 * F;
    float* Bc    = stats + 3 * F;

    k_init<<<1, 256, 0, stream>>>(stats);
    k_wprep<<<32, 256, 0, stream>>>(Wm, Wt);
    k_hist1<<<B1, 1024, 0, stream>>>(ei + NE, mat);
    k_scan1<<<1, 1024, 0, stream>>>(mat);
    k_scat1<<<B1, 1024, 0, stream>>>(ei, mat, ebuf);
    k_fill2<<<NBKT, 1024, 0, stream>>>(mat, ebuf, row_start, dis, csr);
    k_gemm<<<(NN + 127) / 128, 256, 0, stream>>>(x, Wt, dis, (unsigned short*)g);
    k_gather<<<NN / 4, 256, 0, stream>>>(g, csr, row_start, dis, b, out);
    k_stats<<<1024, 256, 0, stream>>>(out, sums, sumsq);
    k_finstats<<<1, F, 0, stream>>>(sums, sumsq, gw, gb, gms, A, Bc);
    k_final<<<2048, 256, 0, stream>>>(out, A, Bc);
    k_eicopy<<<2048, 256, 0, stream>>>(ei, out1);
}

// Round 5
// 231.133 us; speedup vs baseline: 2.6197x; 1.1797x over previous
//
#include <hip/hip_runtime.h>

#define NN 100000
#define NE 1600000
#define F  128

// radix partition params
#define SH   10                 // bucket = dst >> 10
#define NPB  1024               // nodes per bucket
#define NBKT 98                 // ceil(NN/1024)
#define B1   256                // pass-1 blocks
#define CH1  6250               // NE / B1 exactly

constexpr float EPS   = 1e-5f;
constexpr float SLOPE = 0.01f;

typedef __attribute__((ext_vector_type(8))) short short8;
typedef __attribute__((ext_vector_type(4))) float f32x4;

__device__ inline unsigned int bf16rne(float f) {
    unsigned int u = __float_as_uint(f);
    return (u + 0x7fffu + ((u >> 16) & 1u)) >> 16;
}
__device__ inline float blo(unsigned int u) { return __uint_as_float(u << 16); }
__device__ inline float bhi(unsigned int u) { return __uint_as_float(u & 0xffff0000u); }

// ---------------- W prep (fragment-ordered bf16 tiles) + zero stats ----------------
__global__ void k_wprep(const float* __restrict__ Wm, unsigned int* __restrict__ Wt,
                        float* __restrict__ stats) {
    int idx = blockIdx.x * 256 + threadIdx.x;   // 8192 total
    if (blockIdx.x == 0 && threadIdx.x < 2 * F) stats[threadIdx.x] = 0.0f;
    int p = idx & 3, lane = (idx >> 2) & 63, n = (idx >> 8) & 7, kk = idx >> 11;
    int k0 = kk * 32 + (lane >> 4) * 8 + 2 * p;
    int c  = n * 16 + (lane & 15);
    unsigned int lo = bf16rne(Wm[k0 * F + c]);
    unsigned int hi = bf16rne(Wm[(k0 + 1) * F + c]);
    Wt[idx] = lo | (hi << 16);
}

// ---------------- pass 1a: per-block bucket histogram (LDS, no global atomics) ----------------
__global__ __launch_bounds__(1024) void k_hist1(const int* __restrict__ dst,
                                                unsigned int* __restrict__ mat) {
    __shared__ unsigned int h[NBKT];
    if (threadIdx.x < NBKT) h[threadIdx.x] = 0u;
    __syncthreads();
    const int e0 = blockIdx.x * CH1;
    for (int i = threadIdx.x; i < CH1; i += 1024)
        atomicAdd(&h[dst[e0 + i] >> SH], 1u);
    __syncthreads();
    if (threadIdx.x < NBKT) mat[threadIdx.x * B1 + blockIdx.x] = h[threadIdx.x];
}

// ---------------- pass 1b: exclusive scan of (bucket,block) matrix ----------------
__global__ __launch_bounds__(1024) void k_scan1(unsigned int* __restrict__ mat) {
    __shared__ unsigned int ps[1024];
    const int t = threadIdx.x;
    const int total = NBKT * B1;          // 25088
    const int SER = 25;
    int lo = t * SER, hi = min(lo + SER, total);
    unsigned int loc[SER];
    unsigned int s = 0u;
    for (int i = lo; i < hi; ++i) { loc[i - lo] = mat[i]; s += loc[i - lo]; }
    ps[t] = s;
    __syncthreads();
    for (int off = 1; off < 1024; off <<= 1) {
        unsigned int a = (t >= off) ? ps[t - off] : 0u;
        __syncthreads();
        ps[t] += a;
        __syncthreads();
    }
    unsigned int run = (t == 0) ? 0u : ps[t - 1];
    for (int i = lo; i < hi; ++i) { unsigned int v = loc[i - lo]; mat[i] = run; run += v; }
}

// ---------------- pass 1c: scatter edges into bucket segments ----------------
__global__ __launch_bounds__(1024) void k_scat1(const int* __restrict__ ei,
                                                const unsigned int* __restrict__ mat,
                                                unsigned int* __restrict__ ebuf) {
    __shared__ unsigned int cur[NBKT];
    if (threadIdx.x < NBKT) cur[threadIdx.x] = mat[threadIdx.x * B1 + blockIdx.x];
    __syncthreads();
    const int e0 = blockIdx.x * CH1;
    for (int i = threadIdx.x; i < CH1; i += 1024) {
        int s = ei[e0 + i];
        int d = ei[NE + e0 + i];
        unsigned int pos = atomicAdd(&cur[d >> SH], 1u);
        ebuf[pos] = ((unsigned int)(d & (NPB - 1)) << 17) | (unsigned int)s;
    }
}

// ---------------- pass 2: per-bucket degree/scan/row_start/dis + csr fill ----------------
__global__ __launch_bounds__(1024) void k_fill2(const unsigned int* __restrict__ mat,
                                                const unsigned int* __restrict__ ebuf,
                                                int* __restrict__ row_start,
                                                float* __restrict__ dis,
                                                int* __restrict__ csr) {
    __shared__ unsigned int hist[NPB];
    __shared__ unsigned int cur[NPB];
    __shared__ unsigned int ps[1024];
    const int t = threadIdx.x;
    const int bkt = blockIdx.x;
    const int nb0 = bkt << SH;
    hist[t] = 0u;
    __syncthreads();
    const unsigned int ebase = mat[bkt * B1];
    const unsigned int eend  = (bkt == NBKT - 1) ? (unsigned int)NE : mat[(bkt + 1) * B1];
    for (unsigned int i = ebase + t; i < eend; i += 1024)
        atomicAdd(&hist[ebuf[i] >> 17], 1u);
    __syncthreads();
    const unsigned int deg = hist[t];
    ps[t] = deg;
    __syncthreads();
    for (int off = 1; off < 1024; off <<= 1) {
        unsigned int a = (t >= off) ? ps[t - off] : 0u;
        __syncthreads();
        ps[t] += a;
        __syncthreads();
    }
    const unsigned int ex = (t == 0) ? 0u : ps[t - 1];
    cur[t] = ebase + ex;
    const int node = nb0 + t;
    if (node < NN) {
        row_start[node] = (int)(ebase + ex);
        dis[node] = rsqrtf((float)(deg + 1u));
    }
    if (bkt == NBKT - 1 && t == 0) row_start[NN] = NE;
    __syncthreads();
    for (unsigned int i = ebase + t; i < eend; i += 1024) {
        unsigned int v = ebuf[i];
        unsigned int pos = atomicAdd(&cur[v >> 17], 1u);
        csr[pos] = (int)(v & 0x1FFFFu);
    }
}

// ---------------- MFMA GEMM: g = bf16(x @ W) * dis ----------------
// x tile staged coalesced -> bf16 LDS (XOR-swizzled); W fragments from global (L2-hot)
__global__ __launch_bounds__(256) void k_gemm(const float* __restrict__ x,
                                              const unsigned int* __restrict__ Wt,
                                              const float* __restrict__ dis,
                                              unsigned short* __restrict__ g16) {
    __shared__ unsigned int xl[128 * 64];   // 32 KB bf16-pair tile
    const int tid = threadIdx.x;
    const int lane = tid & 63, wave = tid >> 6;
    const int row0 = blockIdx.x * 128;

    // stage: fully coalesced float4 loads, RNE->bf16, swizzled ds_write_b64
#pragma unroll
    for (int i = 0; i < 16; ++i) {
        int fi = i * 256 + tid;            // 0..4095
        int lr = fi >> 5;                  // local row (32 thr/row)
        int cf = (fi & 31) * 4;            // f32 col
        int gr = row0 + lr; if (gr >= NN) gr = NN - 1;
        float4 v = *(const float4*)(x + (size_t)gr * F + cf);
        unsigned int u0 = bf16rne(v.x) | (bf16rne(v.y) << 16);
        unsigned int u1 = bf16rne(v.z) | (bf16rne(v.w) << 16);
        int cu = (cf >> 1) ^ ((lr & 7) << 2);
        uint2 w2; w2.x = u0; w2.y = u1;
        *(uint2*)&xl[lr * 64 + cu] = w2;
    }
    __syncthreads();

    // A fragments from LDS (swizzled, conflict-light ds_read_b128)
    const int rbase = row0 + wave * 32;
    short8 afr[2][4];
#pragma unroll
    for (int m = 0; m < 2; ++m) {
        int lr = wave * 32 + m * 16 + (lane & 15);
#pragma unroll
        for (int kk = 0; kk < 4; ++kk) {
            int cu = (kk * 16 + (lane >> 4) * 4) ^ ((lr & 7) << 2);
            afr[m][kk] = *(const short8*)&xl[lr * 64 + cu];
        }
    }

    f32x4 acc[2][8];
#pragma unroll
    for (int m = 0; m < 2; ++m)
#pragma unroll
        for (int n = 0; n < 8; ++n) { f32x4 z = {0.f, 0.f, 0.f, 0.f}; acc[m][n] = z; }

    const uint4* Wt4 = (const uint4*)Wt;
#pragma unroll
    for (int kk = 0; kk < 4; ++kk) {
        union { uint4 u; short8 s; } bfr[8];
#pragma unroll
        for (int n = 0; n < 8; ++n) bfr[n].u = Wt4[(kk * 8 + n) * 64 + lane];
#pragma unroll
        for (int m = 0; m < 2; ++m)
#pragma unroll
            for (int n = 0; n < 8; ++n)
                acc[m][n] = __builtin_amdgcn_mfma_f32_16x16x32_bf16(afr[m][kk], bfr[n].s, acc[m][n], 0, 0, 0);
    }

    float dv[2][4];
#pragma unroll
    for (int m = 0; m < 2; ++m)
#pragma unroll
        for (int r = 0; r < 4; ++r) {
            int row = rbase + m * 16 + (lane >> 4) * 4 + r;
            dv[m][r] = (row < NN) ? dis[row] : 0.0f;
        }
#pragma unroll
    for (int m = 0; m < 2; ++m)
#pragma unroll
        for (int n = 0; n < 8; ++n)
#pragma unroll
            for (int r = 0; r < 4; ++r) {
                int row = rbase + m * 16 + (lane >> 4) * 4 + r;
                if (row < NN) {
                    int col = n * 16 + (lane & 15);
                    g16[(size_t)row * F + col] = (unsigned short)bf16rne(acc[m][n][r] * dv[m][r]);
                }
            }
}

// ---------------- gather: out = b + dis[n]*sum(g[src] over src ∪ {n}) ----------------
// wave per node; 4 sources/iter; 16 lanes cover one 256B row with uint4;
// quarter-reduce via shfl_xor(16,32); lanes 0-15 write the full 512B row.
__global__ __launch_bounds__(256) void k_gather(const unsigned int* __restrict__ g,
                                                const int* __restrict__ csr,
                                                const int* __restrict__ row_start,
                                                const float* __restrict__ dis,
                                                const float* __restrict__ b,
                                                float* __restrict__ out) {
    const int lane = threadIdx.x & 63;
    const int node = blockIdx.x * 4 + (threadIdx.x >> 6);
    if (node >= NN) return;
    const int q = lane >> 4;           // source slot within iteration
    const int c = lane & 15;           // uint4 column: features 8c..8c+7
    const int j = row_start[node];
    const int e = row_start[node + 1];
    const int L = e - j + 1;           // + self
    float a0 = 0.f, a1 = 0.f, a2 = 0.f, a3 = 0.f;
    float a4 = 0.f, a5 = 0.f, a6 = 0.f, a7 = 0.f;
    for (int k = 0; k < L; k += 4) {
        int idx = j + k + q;
        int row = (idx < e) ? csr[idx] : node;
        if (k + q < L) {
            uint4 v = *(const uint4*)&g[(size_t)row * 64 + c * 4];
            a0 += blo(v.x); a1 += bhi(v.x);
            a2 += blo(v.y); a3 += bhi(v.y);
            a4 += blo(v.z); a5 += bhi(v.z);
            a6 += blo(v.w); a7 += bhi(v.w);
        }
    }
    a0 += __shfl_xor(a0, 16); a0 += __shfl_xor(a0, 32);
    a1 += __shfl_xor(a1, 16); a1 += __shfl_xor(a1, 32);
    a2 += __shfl_xor(a2, 16); a2 += __shfl_xor(a2, 32);
    a3 += __shfl_xor(a3, 16); a3 += __shfl_xor(a3, 32);
    a4 += __shfl_xor(a4, 16); a4 += __shfl_xor(a4, 32);
    a5 += __shfl_xor(a5, 16); a5 += __shfl_xor(a5, 32);
    a6 += __shfl_xor(a6, 16); a6 += __shfl_xor(a6, 32);
    a7 += __shfl_xor(a7, 16); a7 += __shfl_xor(a7, 32);
    if (q == 0) {
        float d = dis[node];
        float4 b0 = *(const float4*)&b[c * 8];
        float4 b1 = *(const float4*)&b[c * 8 + 4];
        float4 r0, r1;
        r0.x = b0.x + d * a0; r0.y = b0.y + d * a1;
        r0.z = b0.z + d * a2; r0.w = b0.w + d * a3;
        r1.x = b1.x + d * a4; r1.y = b1.y + d * a5;
        r1.z = b1.z + d * a6; r1.w = b1.w + d * a7;
        *(float4*)&out[(size_t)node * F + c * 8]     = r0;
        *(float4*)&out[(size_t)node * F + c * 8 + 4] = r1;
    }
}

// ---------------- per-feature sums / sumsq ----------------
__global__ __launch_bounds__(256) void k_stats(const float* __restrict__ agg,
                                               float* __restrict__ sums,
                                               float* __restrict__ sumsq) {
    __shared__ float red[2][F];
    const int tx = threadIdx.x & 127;
    const int ty = threadIdx.x >> 7;
    float s = 0.0f, s2 = 0.0f;
    for (int row = blockIdx.x * 2 + ty; row < NN; row += gridDim.x * 2) {
        float v = agg[(long)row * F + tx];
        s += v;
        s2 += v * v;
    }
    red[ty][tx] = s;
    __syncthreads();
    if (ty == 0) atomicAdd(&sums[tx], s + red[1][tx]);
    __syncthreads();
    red[ty][tx] = s2;
    __syncthreads();
    if (ty == 0) atomicAdd(&sumsq[tx], s2 + red[1][tx]);
}

// ---------------- finalize stats -> per-feature affine ----------------
__global__ void k_finstats(const float* __restrict__ sums, const float* __restrict__ sumsq,
                           const float* __restrict__ gw, const float* __restrict__ gb,
                           const float* __restrict__ gms,
                           float* __restrict__ A, float* __restrict__ Bc) {
    int f = threadIdx.x;
    if (f < F) {
        const float invn = 1.0f / (float)NN;
        float mean = sums[f] * invn;
        float ms = mean * gms[f];
        float var = sumsq[f] * invn - 2.0f * ms * mean + ms * ms;
        float inv = rsqrtf(var + EPS);
        float a = inv * gw[f];
        A[f] = a;
        Bc[f] = gb[f] - ms * a;
    }
}

// ---------------- fused: GraphNorm affine + LeakyReLU  |  edge_index -> float ----------------
__global__ void k_finish(float* __restrict__ out, const float* __restrict__ A,
                         const float* __restrict__ Bc, const int* __restrict__ ei,
                         float* __restrict__ out1) {
    const long t0 = (long)NN * F / 4;
    const long t1 = 2L * NE / 4;
    float4* o4 = (float4*)out;
    const float4* A4 = (const float4*)A;
    const float4* B4 = (const float4*)Bc;
    const int4* i4 = (const int4*)ei;
    float4* o14 = (float4*)out1;
    for (long i = (long)blockIdx.x * blockDim.x + threadIdx.x; i < t0 + t1;
         i += (long)gridDim.x * blockDim.x) {
        if (i < t0) {
            int f4 = (int)(i & 31);
            float4 v = o4[i];
            float4 a = A4[f4];
            float4 bc = B4[f4];
            v.x = v.x * a.x + bc.x; v.x = v.x > 0.f ? v.x : SLOPE * v.x;
            v.y = v.y * a.y + bc.y; v.y = v.y > 0.f ? v.y : SLOPE * v.y;
            v.z = v.z * a.z + bc.z; v.z = v.z > 0.f ? v.z : SLOPE * v.z;
            v.w = v.w * a.w + bc.w; v.w = v.w > 0.f ? v.w : SLOPE * v.w;
            o4[i] = v;
        } else {
            long k = i - t0;
            int4 v = i4[k];
            float4 r;
            r.x = (float)v.x; r.y = (float)v.y; r.z = (float)v.z; r.w = (float)v.w;
            o14[k] = r;
        }
    }
}

extern "C" void kernel_launch(void* const* d_in, const int* in_sizes, int n_in,
                              void* d_out, int out_size, void* d_ws, size_t ws_size,
                              hipStream_t stream) {
    const float* x   = (const float*)d_in[0];
    const int*   ei  = (const int*)d_in[1];
    const float* Wm  = (const float*)d_in[2];
    const float* b   = (const float*)d_in[3];
    const float* gw  = (const float*)d_in[4];
    const float* gb  = (const float*)d_in[5];
    const float* gms = (const float*)d_in[6];

    float* out  = (float*)d_out;                 // region0: NN*F, region1: 2*NE
    float* out1 = out + (size_t)NN * F;

    // ws layout (u32 units). ebuf aliases g: ebuf consumed by k_fill2 before k_gemm writes g.
    unsigned int* wsu   = (unsigned int*)d_ws;
    unsigned int* g     = wsu;                          // NN*64 u32 (25.6 MB)
    unsigned int* ebuf  = wsu;                          // NE u32 (6.4 MB) — alias of g
    unsigned int* mat   = g + (size_t)NN * 64;          // NBKT*B1 = 25088
    int* row_start      = (int*)(mat + NBKT * B1 + 64); // NN+1
    int* csr            = row_start + NN + 2;           // NE (+8 pad)
    float* dis          = (float*)(csr + NE + 8);       // NN
    float* stats        = dis + NN;                     // 512
    unsigned int* Wt    = (unsigned int*)(stats + 512); // 8192
    float* sums  = stats;
    float* sumsq = stats + F;
    float* A     = stats + 2 * F;
    float* Bc    = stats + 3 * F;

    k_wprep<<<32, 256, 0, stream>>>(Wm, Wt, stats);
    k_hist1<<<B1, 1024, 0, stream>>>(ei + NE, mat);
    k_scan1<<<1, 1024, 0, stream>>>(mat);
    k_scat1<<<B1, 1024, 0, stream>>>(ei, mat, ebuf);
    k_fill2<<<NBKT, 1024, 0, stream>>>(mat, ebuf, row_start, dis, csr);
    k_gemm<<<(NN + 127) / 128, 256, 0, stream>>>(x, Wt, dis, (unsigned short*)g);
    k_gather<<<NN / 4, 256, 0, stream>>>(g, csr, row_start, dis, b, out);
    k_stats<<<1024, 256, 0, stream>>>(out, sums, sumsq);
    k_finstats<<<1, F, 0, stream>>>(sums, sumsq, gw, gb, gms, A, Bc);
    k_finish<<<2048, 256, 0, stream>>>(out, A, Bc, ei, out1);
}